// Round 5
// baseline (125.566 us; speedup 1.0000x reference)
//
#include <hip/hip_runtime.h>

#define SS 2704                // 52*52
#define NA 5
#define NC 20
#define NB 128
#define CELLS (NB * SS)        // 346112
#define TILE 64                // cells per tile
#define TPB 320                // 5 waves; wave index == anchor index
#define NTILE (CELLS / TILE)   // 5408
#define TPB_TILES 4            // tiles per block (pipelined)
#define NBLK (NTILE / TPB_TILES) // 1352 exactly
#define TILE_F (TILE * 125)    // 8000 floats = 32 KB
#define TILE_V4 (TILE_F / 4)   // 2000 float4
#define RBLOCK 1024

__device__ __forceinline__ float fast_sigmoid(float x) {
    return __builtin_amdgcn_rcpf(1.0f + __expf(-x));
}
__device__ __forceinline__ float fast_softplus(float x) {
    // logaddexp(0,x) = max(x,0) + log(1 + exp(-|x|)); all HW instrs
    return fmaxf(x, 0.0f) + __logf(1.0f + __expf(-fabsf(x)));
}

// partial layout per block: [xywh, cls, obj, noobj]
__global__ __launch_bounds__(TPB) void yolo_main(
        const float* __restrict__ P,      // (B, 125, S, S)
        const float* __restrict__ T,      // (B, S, S, 5, 25)
        const float* __restrict__ anch,   // (5, 2)
        float* __restrict__ partial) {
    __shared__ float lds[TILE_F];
    __shared__ float red[NA][4];

    int a    = threadIdx.x >> 6;          // 0..4, wave-uniform
    int lane = threadIdx.x & 63;
    float aw  = anch[2 * a];
    float ahv = anch[2 * a + 1];

    int tile0 = blockIdx.x * TPB_TILES;
    int cell  = tile0 * TILE + lane;
    int b     = cell / SS;                 // one divide; then incremental
    int ij    = cell - b * SS;

    float s_xywh = 0.0f, s_cls = 0.0f, s_obj = 0.0f, s_noobj = 0.0f;

    // ---- prologue: issue tile0's T loads into regs ----
    float4 stg[7];
    {
        const float4* src = (const float4*)(T + (size_t)tile0 * TILE_F);
        #pragma unroll
        for (int i = 0; i < 7; ++i) {
            int idx = threadIdx.x + i * TPB;
            if (idx < TILE_V4) stg[i] = src[idx];
        }
    }

    for (int k = 0; k < TPB_TILES; ++k) {
        // ---- write staged regs -> LDS (vmcnt wait auto-inserted) ----
        {
            float4* dst = (float4*)lds;
            #pragma unroll
            for (int i = 0; i < 7; ++i) {
                int idx = threadIdx.x + i * TPB;
                if (idx < TILE_V4) dst[idx] = stg[i];
            }
        }
        __syncthreads();

        // ---- issue NEXT tile's T loads (in flight across this compute) ----
        if (k + 1 < TPB_TILES) {
            const float4* src = (const float4*)(T + (size_t)(tile0 + k + 1) * TILE_F);
            #pragma unroll
            for (int i = 0; i < 7; ++i) {
                int idx = threadIdx.x + i * TPB;
                if (idx < TILE_V4) stg[i] = src[idx];
            }
        }

        // ---- compute this tile ----
        const float* Pa = P + ((size_t)b * 125 + a * 25) * SS + ij;
        const float* Tl = lds + lane * 125 + a * 25;   // stride 125: bank-bijective

        float fl = Tl[4];
        float cp = fast_sigmoid(Pa[4 * SS]);           // coalesced 64-float span

        if (fl != 0.0f) {
            float tx = Pa[0], ty = Pa[SS], tw = Pa[2 * SS], th = Pa[3 * SS];
            float gx = Tl[0], gy = Tl[1], gw = Tl[2], gh = Tl[3];
            float cx = fast_sigmoid(tx), cy = fast_sigmoid(ty);
            float pw = __expf(tw) * aw;
            float ph = __expf(th) * ahv;
            // IoU invariant to common (+j,+i) shift -> dropped.
            float iw = fmaxf(fminf(gx + 0.5f * gw, cx + 0.5f * pw) -
                             fmaxf(gx - 0.5f * gw, cx - 0.5f * pw), 0.0f);
            float ih = fmaxf(fminf(gy + 0.5f * gh, cy + 0.5f * ph) -
                             fmaxf(gy - 0.5f * gh, cy - 0.5f * ph), 0.0f);
            float inter = iw * ih;
            float uni   = gw * gh + pw * ph - inter;
            float iou   = (uni > 0.0f) ? inter * __builtin_amdgcn_rcpf(uni) : 0.0f;

            float dx = cx - gx, dy = cy - gy;
            s_xywh += dx * dx + dy * dy;
            const float eps = 1e-6f;
            float dw = __fsqrt_rn(pw + eps) - __fsqrt_rn(gw + eps);
            float dh = __fsqrt_rn(ph + eps) - __fsqrt_rn(gh + eps);
            s_xywh += dw * dw + dh * dh;

            float dob = iou - cp;
            s_obj += dob * dob;

            #pragma unroll
            for (int c = 0; c < NC; ++c) {
                float l = Pa[(size_t)(5 + c) * SS];
                float t = Tl[5 + c];
                s_cls += fast_softplus(l) - l * t;
            }
        } else {
            s_noobj += cp * cp;
        }

        __syncthreads();   // protect lds before next tile's write

        // incremental cell advance (TILE=64 < SS)
        ij += TILE;
        if (ij >= SS) { ij -= SS; b += 1; }
    }

    // ---- wave reduce (64 lanes), then cross-wave via LDS ----
    #pragma unroll
    for (int off = 32; off > 0; off >>= 1) {
        s_xywh  += __shfl_xor(s_xywh,  off, 64);
        s_cls   += __shfl_xor(s_cls,   off, 64);
        s_obj   += __shfl_xor(s_obj,   off, 64);
        s_noobj += __shfl_xor(s_noobj, off, 64);
    }
    if (lane == 0) {
        red[a][0] = s_xywh; red[a][1] = s_cls; red[a][2] = s_obj; red[a][3] = s_noobj;
    }
    __syncthreads();
    if (threadIdx.x == 0) {
        float r0 = 0, r1 = 0, r2 = 0, r3 = 0;
        #pragma unroll
        for (int w = 0; w < NA; ++w) {
            r0 += red[w][0]; r1 += red[w][1]; r2 += red[w][2]; r3 += red[w][3];
        }
        float* p = partial + (size_t)blockIdx.x * 4;
        p[0] = r0; p[1] = r1; p[2] = r2; p[3] = r3;
    }
}

__global__ __launch_bounds__(RBLOCK) void yolo_reduce(
        const float* __restrict__ partial, int n, float* __restrict__ out) {
    float v0 = 0.0f, v1 = 0.0f, v2 = 0.0f, v3 = 0.0f;
    for (int i = threadIdx.x; i < n; i += RBLOCK) {
        const float* p = partial + (size_t)i * 4;
        v0 += p[0]; v1 += p[1]; v2 += p[2]; v3 += p[3];
    }
    #pragma unroll
    for (int off = 32; off > 0; off >>= 1) {
        v0 += __shfl_xor(v0, off, 64);
        v1 += __shfl_xor(v1, off, 64);
        v2 += __shfl_xor(v2, off, 64);
        v3 += __shfl_xor(v3, off, 64);
    }
    __shared__ float red[16][4];
    int wid = threadIdx.x >> 6, lane = threadIdx.x & 63;
    if (lane == 0) {
        red[wid][0] = v0; red[wid][1] = v1; red[wid][2] = v2; red[wid][3] = v3;
    }
    __syncthreads();
    if (threadIdx.x == 0) {
        float xywh = 0, cls = 0, obj = 0, noobj = 0;
        #pragma unroll
        for (int q = 0; q < RBLOCK / 64; ++q) {
            xywh += red[q][0]; cls += red[q][1]; obj += red[q][2]; noobj += red[q][3];
        }
        out[0] = 5.0f * xywh + 5.0f * obj + 0.5f * noobj + cls;
        out[1] = xywh;
        out[2] = cls;
        out[3] = obj + noobj;
    }
}

extern "C" void kernel_launch(void* const* d_in, const int* in_sizes, int n_in,
                              void* d_out, int out_size, void* d_ws, size_t ws_size,
                              hipStream_t stream) {
    const float* P = (const float*)d_in[0];
    const float* T = (const float*)d_in[1];
    const float* anch = (const float*)d_in[2];
    float* out = (float*)d_out;
    float* partial = (float*)d_ws;   // NBLK * 4 floats = 21.6 KB

    yolo_main<<<NBLK, TPB, 0, stream>>>(P, T, anch, partial);
    yolo_reduce<<<1, RBLOCK, 0, stream>>>(partial, NBLK, out);
}

// Round 6
// 120.643 us; speedup vs baseline: 1.0408x; 1.0408x over previous
//
#include <hip/hip_runtime.h>
#include <stdint.h>

#define SS 2704                   // 52*52
#define NA 5
#define NC 20
#define NB 128
#define CELLS (NB * SS)           // 346112
#define TILE 64                   // cells per tile
#define NTILE (CELLS / TILE)      // 5408
#define TILES_PER_BLK 4
#define NBLK (NTILE / TILES_PER_BLK)  // 1352 exactly
#define TPB 320                   // 5 waves; wave index == anchor index
#define TILE_BYTES (TILE * 125 * 4)   // 32000 B per tile slab
#define CHUNKS 32                 // ceil(32000 / 1024); chunk = 64 lanes x 16 B
#define BUF_FLOATS 8192           // padded to 32768 B (chunk 31 writes into pad)
#define RBLOCK 1024

__device__ __forceinline__ float fast_sigmoid(float x) {
    return __builtin_amdgcn_rcpf(1.0f + __expf(-x));
}
__device__ __forceinline__ float fast_softplus(float x) {
    // logaddexp(0,x) = max(x,0) + log(1 + exp(-|x|)); all HW instrs
    return fmaxf(x, 0.0f) + __logf(1.0f + __expf(-fabsf(x)));
}

__device__ __forceinline__ void gl_lds16(const void* g, void* l) {
    __builtin_amdgcn_global_load_lds(
        (const __attribute__((address_space(1))) void*)g,
        (__attribute__((address_space(3))) void*)l, 16, 0, 0);
}

// Stage one 32000 B T-tile into lbuf. Wave-uniform LDS base + lane*16 (the
// required global_load_lds pattern); per-lane global guard for the array end.
__device__ __forceinline__ void stage_tile(const char* __restrict__ Tb,
                                           size_t t_total_bytes,
                                           int tile, float* lbuf,
                                           int wave, int lane) {
    const char* tbase = Tb + (size_t)tile * TILE_BYTES;
    #pragma unroll
    for (int i = 0; i < 7; ++i) {
        int c = wave * 7 + i;                 // wave-uniform chunk id
        if (c < CHUNKS) {
            size_t goff = (size_t)c * 1024 + (size_t)lane * 16;
            const char* g = tbase + goff;
            if (g + 16 <= Tb + t_total_bytes)   // masks only final tile's pad lanes
                gl_lds16(g, (char*)lbuf + c * 1024);
        }
    }
}

// partial layout per block: [xywh, cls, obj, noobj]
__global__ __launch_bounds__(TPB) void yolo_main(
        const float* __restrict__ P,      // (B, 125, S, S)
        const float* __restrict__ T,      // (B, S, S, 5, 25)
        const float* __restrict__ anch,   // (5, 2)
        float* __restrict__ partial) {
    __shared__ float lds[2][BUF_FLOATS];  // 65.5 KB, double-buffered
    __shared__ float red[NA][4];

    int a    = threadIdx.x >> 6;          // wave index == anchor, 0..4
    int lane = threadIdx.x & 63;
    float aw  = anch[2 * a];
    float ahv = anch[2 * a + 1];

    int tile0 = blockIdx.x * TILES_PER_BLK;
    int cell  = tile0 * TILE + lane;
    int b     = cell / SS;                // one divide; then incremental
    int ij    = cell - b * SS;

    const char* Tb = (const char*)T;
    const size_t Tbytes = (size_t)CELLS * 500;

    float s_xywh = 0.0f, s_cls = 0.0f, s_obj = 0.0f, s_noobj = 0.0f;

    // prologue: stage tile0, full drain+barrier
    stage_tile(Tb, Tbytes, tile0, lds[0], a, lane);
    __syncthreads();

    for (int k = 0; k < TILES_PER_BLK; ++k) {
        int cur = k & 1;

        // issue NEXT tile's loads FIRST -- they fly under this tile's compute;
        // the end-of-iter __syncthreads drains only the residue.
        if (k + 1 < TILES_PER_BLK)
            stage_tile(Tb, Tbytes, tile0 + k + 1, lds[cur ^ 1], a, lane);

        // ---- compute tile k from lds[cur] ----
        const float* Pa = P + ((size_t)b * 125 + a * 25) * SS + ij;
        const float* Tl = lds[cur] + lane * 125 + a * 25;  // stride 125: bank-bijective

        float fl = Tl[4];
        float cp = fast_sigmoid(Pa[4 * SS]);               // coalesced span

        if (fl != 0.0f) {
            float tx = Pa[0], ty = Pa[SS], tw = Pa[2 * SS], th = Pa[3 * SS];
            float gx = Tl[0], gy = Tl[1], gw = Tl[2], gh = Tl[3];
            float cx = fast_sigmoid(tx), cy = fast_sigmoid(ty);
            float pw = __expf(tw) * aw;
            float ph = __expf(th) * ahv;
            // IoU invariant to common (+j,+i) shift -> dropped.
            float iw = fmaxf(fminf(gx + 0.5f * gw, cx + 0.5f * pw) -
                             fmaxf(gx - 0.5f * gw, cx - 0.5f * pw), 0.0f);
            float ih = fmaxf(fminf(gy + 0.5f * gh, cy + 0.5f * ph) -
                             fmaxf(gy - 0.5f * gh, cy - 0.5f * ph), 0.0f);
            float inter = iw * ih;
            float uni   = gw * gh + pw * ph - inter;
            float iou   = (uni > 0.0f) ? inter * __builtin_amdgcn_rcpf(uni) : 0.0f;

            float dx = cx - gx, dy = cy - gy;
            s_xywh += dx * dx + dy * dy;
            const float eps = 1e-6f;
            float dw = __fsqrt_rn(pw + eps) - __fsqrt_rn(gw + eps);
            float dh = __fsqrt_rn(ph + eps) - __fsqrt_rn(gh + eps);
            s_xywh += dw * dw + dh * dh;

            float dob = iou - cp;
            s_obj += dob * dob;

            #pragma unroll
            for (int c = 0; c < NC; ++c) {
                float l = Pa[(size_t)(5 + c) * SS];
                float t = Tl[5 + c];
                s_cls += fast_softplus(l) - l * t;
            }
        } else {
            s_noobj += cp * cp;
        }

        // drain next-tile loads (mostly done) + protect lds[cur] for overwrite
        __syncthreads();

        ij += TILE;
        if (ij >= SS) { ij -= SS; b += 1; }
    }

    // ---- wave reduce (64 lanes), then cross-wave via LDS ----
    #pragma unroll
    for (int off = 32; off > 0; off >>= 1) {
        s_xywh  += __shfl_xor(s_xywh,  off, 64);
        s_cls   += __shfl_xor(s_cls,   off, 64);
        s_obj   += __shfl_xor(s_obj,   off, 64);
        s_noobj += __shfl_xor(s_noobj, off, 64);
    }
    if (lane == 0) {
        red[a][0] = s_xywh; red[a][1] = s_cls; red[a][2] = s_obj; red[a][3] = s_noobj;
    }
    __syncthreads();
    if (threadIdx.x == 0) {
        float r0 = 0, r1 = 0, r2 = 0, r3 = 0;
        #pragma unroll
        for (int w = 0; w < NA; ++w) {
            r0 += red[w][0]; r1 += red[w][1]; r2 += red[w][2]; r3 += red[w][3];
        }
        float* p = partial + (size_t)blockIdx.x * 4;
        p[0] = r0; p[1] = r1; p[2] = r2; p[3] = r3;
    }
}

__global__ __launch_bounds__(RBLOCK) void yolo_reduce(
        const float* __restrict__ partial, int n, float* __restrict__ out) {
    float v0 = 0.0f, v1 = 0.0f, v2 = 0.0f, v3 = 0.0f;
    for (int i = threadIdx.x; i < n; i += RBLOCK) {
        const float* p = partial + (size_t)i * 4;
        v0 += p[0]; v1 += p[1]; v2 += p[2]; v3 += p[3];
    }
    #pragma unroll
    for (int off = 32; off > 0; off >>= 1) {
        v0 += __shfl_xor(v0, off, 64);
        v1 += __shfl_xor(v1, off, 64);
        v2 += __shfl_xor(v2, off, 64);
        v3 += __shfl_xor(v3, off, 64);
    }
    __shared__ float red[RBLOCK / 64][4];
    int wid = threadIdx.x >> 6, lane = threadIdx.x & 63;
    if (lane == 0) {
        red[wid][0] = v0; red[wid][1] = v1; red[wid][2] = v2; red[wid][3] = v3;
    }
    __syncthreads();
    if (threadIdx.x == 0) {
        float xywh = 0, cls = 0, obj = 0, noobj = 0;
        #pragma unroll
        for (int q = 0; q < RBLOCK / 64; ++q) {
            xywh += red[q][0]; cls += red[q][1]; obj += red[q][2]; noobj += red[q][3];
        }
        out[0] = 5.0f * xywh + 5.0f * obj + 0.5f * noobj + cls;
        out[1] = xywh;
        out[2] = cls;
        out[3] = obj + noobj;
    }
}

extern "C" void kernel_launch(void* const* d_in, const int* in_sizes, int n_in,
                              void* d_out, int out_size, void* d_ws, size_t ws_size,
                              hipStream_t stream) {
    const float* P = (const float*)d_in[0];
    const float* T = (const float*)d_in[1];
    const float* anch = (const float*)d_in[2];
    float* out = (float*)d_out;
    float* partial = (float*)d_ws;   // NBLK * 4 floats = 21.6 KB

    yolo_main<<<NBLK, TPB, 0, stream>>>(P, T, anch, partial);
    yolo_reduce<<<1, RBLOCK, 0, stream>>>(partial, NBLK, out);
}

// Round 7
// 59.328 us; speedup vs baseline: 2.1165x; 2.0335x over previous
//
#include <hip/hip_runtime.h>

#define SS 2704                // 52*52
#define NA 5
#define NC 20
#define NB 128
#define CELLS (NB * SS)        // 346112
#define TILE 64                // cells per block
#define TPB 320                // 5 waves; wave index == anchor index
#define NBLK (CELLS / TILE)    // 5408
#define RBLOCK 1024

__device__ __forceinline__ float fast_sigmoid(float x) {
    return __builtin_amdgcn_rcpf(1.0f + __expf(-x));
}
__device__ __forceinline__ float fast_softplus(float x) {
    // logaddexp(0,x) = max(x,0) + log(1 + exp(-|x|)); all HW instrs
    return fmaxf(x, 0.0f) + __logf(1.0f + __expf(-fabsf(x)));
}

// block = 64-cell tile; wave = anchor; lane = cell-in-tile.
// No LDS staging: the 5 waves of a block touch the same 32KB T-window, so
// scattered record reads are L1-served. No barriers until the final reduce.
__global__ __launch_bounds__(TPB) void yolo_main(
        const float* __restrict__ P,      // (B, 125, S, S)
        const float* __restrict__ T,      // (B, S, S, 5, 25)
        const float* __restrict__ anch,   // (5, 2)
        float* __restrict__ partial) {
    __shared__ float red[NA][4];

    int a    = threadIdx.x >> 6;          // 0..4, wave-uniform
    int lane = threadIdx.x & 63;
    int cell = blockIdx.x * TILE + lane;
    int b    = cell / SS;
    int ij   = cell - b * SS;

    const float* Ta = T + (size_t)cell * 125 + a * 25;            // global record
    const float* Pa = P + ((size_t)b * 125 + a * 25) * SS + ij;   // plane base
    float aw  = anch[2 * a];
    float ahv = anch[2 * a + 1];

    // issue flag + conf immediately (independent, in flight together)
    float fl = Ta[4];
    float cp = fast_sigmoid(Pa[4 * SS]);          // coalesced 64-float span

    float s_xywh = 0.0f, s_cls = 0.0f, s_obj = 0.0f, s_noobj = 0.0f;

    if (fl != 0.0f) {
        float tx = Pa[0], ty = Pa[SS], tw = Pa[2 * SS], th = Pa[3 * SS];
        float gx = Ta[0], gy = Ta[1], gw = Ta[2], gh = Ta[3];
        float cx = fast_sigmoid(tx), cy = fast_sigmoid(ty);
        float pw = __expf(tw) * aw;
        float ph = __expf(th) * ahv;
        // IoU invariant to common (+j,+i) shift -> dropped.
        float iw = fmaxf(fminf(gx + 0.5f * gw, cx + 0.5f * pw) -
                         fmaxf(gx - 0.5f * gw, cx - 0.5f * pw), 0.0f);
        float ih = fmaxf(fminf(gy + 0.5f * gh, cy + 0.5f * ph) -
                         fmaxf(gy - 0.5f * gh, cy - 0.5f * ph), 0.0f);
        float inter = iw * ih;
        float uni   = gw * gh + pw * ph - inter;
        float iou   = (uni > 0.0f) ? inter * __builtin_amdgcn_rcpf(uni) : 0.0f;

        float dx = cx - gx, dy = cy - gy;
        s_xywh += dx * dx + dy * dy;
        const float eps = 1e-6f;
        float dw = __fsqrt_rn(pw + eps) - __fsqrt_rn(gw + eps);
        float dh = __fsqrt_rn(ph + eps) - __fsqrt_rn(gh + eps);
        s_xywh += dw * dw + dh * dh;

        float dob = iou - cp;
        s_obj += dob * dob;

        #pragma unroll
        for (int c = 0; c < NC; ++c) {
            float l = Pa[(size_t)(5 + c) * SS];   // coalesced span (active lanes)
            float t = Ta[5 + c];                  // L1-window hit
            s_cls += fast_softplus(l) - l * t;
        }
    } else {
        s_noobj = cp * cp;
    }

    // ---- wave reduce (64 lanes), then cross-wave via tiny LDS ----
    #pragma unroll
    for (int off = 32; off > 0; off >>= 1) {
        s_xywh  += __shfl_xor(s_xywh,  off, 64);
        s_cls   += __shfl_xor(s_cls,   off, 64);
        s_obj   += __shfl_xor(s_obj,   off, 64);
        s_noobj += __shfl_xor(s_noobj, off, 64);
    }
    if (lane == 0) {
        red[a][0] = s_xywh; red[a][1] = s_cls; red[a][2] = s_obj; red[a][3] = s_noobj;
    }
    __syncthreads();
    if (threadIdx.x == 0) {
        float r0 = 0, r1 = 0, r2 = 0, r3 = 0;
        #pragma unroll
        for (int w = 0; w < NA; ++w) {
            r0 += red[w][0]; r1 += red[w][1]; r2 += red[w][2]; r3 += red[w][3];
        }
        float* p = partial + (size_t)blockIdx.x * 4;
        p[0] = r0; p[1] = r1; p[2] = r2; p[3] = r3;
    }
}

__global__ __launch_bounds__(RBLOCK) void yolo_reduce(
        const float* __restrict__ partial, int n, float* __restrict__ out) {
    float v0 = 0.0f, v1 = 0.0f, v2 = 0.0f, v3 = 0.0f;
    for (int i = threadIdx.x; i < n; i += RBLOCK) {
        const float* p = partial + (size_t)i * 4;
        v0 += p[0]; v1 += p[1]; v2 += p[2]; v3 += p[3];
    }
    #pragma unroll
    for (int off = 32; off > 0; off >>= 1) {
        v0 += __shfl_xor(v0, off, 64);
        v1 += __shfl_xor(v1, off, 64);
        v2 += __shfl_xor(v2, off, 64);
        v3 += __shfl_xor(v3, off, 64);
    }
    __shared__ float red[RBLOCK / 64][4];
    int wid = threadIdx.x >> 6, lane = threadIdx.x & 63;
    if (lane == 0) {
        red[wid][0] = v0; red[wid][1] = v1; red[wid][2] = v2; red[wid][3] = v3;
    }
    __syncthreads();
    if (threadIdx.x == 0) {
        float xywh = 0, cls = 0, obj = 0, noobj = 0;
        #pragma unroll
        for (int q = 0; q < RBLOCK / 64; ++q) {
            xywh += red[q][0]; cls += red[q][1]; obj += red[q][2]; noobj += red[q][3];
        }
        out[0] = 5.0f * xywh + 5.0f * obj + 0.5f * noobj + cls;
        out[1] = xywh;
        out[2] = cls;
        out[3] = obj + noobj;
    }
}

extern "C" void kernel_launch(void* const* d_in, const int* in_sizes, int n_in,
                              void* d_out, int out_size, void* d_ws, size_t ws_size,
                              hipStream_t stream) {
    const float* P = (const float*)d_in[0];
    const float* T = (const float*)d_in[1];
    const float* anch = (const float*)d_in[2];
    float* out = (float*)d_out;
    float* partial = (float*)d_ws;   // NBLK * 4 floats = 86.5 KB

    yolo_main<<<NBLK, TPB, 0, stream>>>(P, T, anch, partial);
    yolo_reduce<<<1, RBLOCK, 0, stream>>>(partial, NBLK, out);
}

// Round 8
// 57.380 us; speedup vs baseline: 2.1883x; 1.0339x over previous
//
#include <hip/hip_runtime.h>

#define SS 2704                // 52*52
#define NA 5
#define NC 20
#define NB 128
#define CELLS (NB * SS)        // 346112
#define TILE 64                // cells per block
#define TPB 320                // 5 waves; wave index == anchor index
#define NBLK (CELLS / TILE)    // 5408
#define RBLOCK 1024

__device__ __forceinline__ float fast_sigmoid(float x) {
    return __builtin_amdgcn_rcpf(1.0f + __expf(-x));
}
__device__ __forceinline__ float fast_softplus(float x) {
    // logaddexp(0,x) = max(x,0) + log(1 + exp(-|x|)); all HW instrs
    return fmaxf(x, 0.0f) + __logf(1.0f + __expf(-fabsf(x)));
}

// block = 64-cell tile; wave = anchor; lane = cell-in-tile. No LDS staging
// (L1 serves the block's shared 32KB T-window). Class loss is wave-compacted:
// ballot the ~3 obj lanes, then spread 3 pairs x 20 class elems over 60 lanes
// per pass -- softplus runs once per pass instead of 20x at 5% lane duty.
__global__ __launch_bounds__(TPB) void yolo_main(
        const float* __restrict__ P,      // (B, 125, S, S)
        const float* __restrict__ T,      // (B, S, S, 5, 25)
        const float* __restrict__ anch,   // (5, 2)
        float* __restrict__ partial) {
    __shared__ float red[NA][4];

    int a    = threadIdx.x >> 6;          // 0..4, wave-uniform
    int lane = threadIdx.x & 63;
    int base_cell = blockIdx.x * TILE;
    int cell = base_cell + lane;
    int b    = cell / SS;
    int ij   = cell - b * SS;
    int b0   = base_cell / SS;            // uniform helpers for pair decode
    int ij0  = base_cell - b0 * SS;

    const float* Ta = T + (size_t)cell * 125 + a * 25;            // record
    const float* Pa = P + ((size_t)b * 125 + a * 25) * SS + ij;   // plane base
    float aw  = anch[2 * a];
    float ahv = anch[2 * a + 1];

    float fl = Ta[4];
    float cp = fast_sigmoid(Pa[4 * SS]);          // coalesced span

    float s_xywh = 0.0f, s_cls = 0.0f, s_obj = 0.0f, s_noobj = 0.0f;
    bool isobj = (fl != 0.0f);

    if (isobj) {
        // ---- gated box / IoU / obj-conf part (~3 lanes) ----
        float tx = Pa[0], ty = Pa[SS], tw = Pa[2 * SS], th = Pa[3 * SS];
        float gx = Ta[0], gy = Ta[1], gw = Ta[2], gh = Ta[3];
        float cx = fast_sigmoid(tx), cy = fast_sigmoid(ty);
        float pw = __expf(tw) * aw;
        float ph = __expf(th) * ahv;
        // IoU invariant to common (+j,+i) shift -> dropped.
        float iw = fmaxf(fminf(gx + 0.5f * gw, cx + 0.5f * pw) -
                         fmaxf(gx - 0.5f * gw, cx - 0.5f * pw), 0.0f);
        float ih = fmaxf(fminf(gy + 0.5f * gh, cy + 0.5f * ph) -
                         fmaxf(gy - 0.5f * gh, cy - 0.5f * ph), 0.0f);
        float inter = iw * ih;
        float uni   = gw * gh + pw * ph - inter;
        float iou   = (uni > 0.0f) ? inter * __builtin_amdgcn_rcpf(uni) : 0.0f;

        float dx = cx - gx, dy = cy - gy;
        s_xywh += dx * dx + dy * dy;
        const float eps = 1e-6f;
        float dw = __fsqrt_rn(pw + eps) - __fsqrt_rn(gw + eps);
        float dh = __fsqrt_rn(ph + eps) - __fsqrt_rn(gh + eps);
        s_xywh += dw * dw + dh * dh;

        float dob = iou - cp;
        s_obj += dob * dob;
    } else {
        s_noobj = cp * cp;
    }

    // ---- wave-compacted class loss ----
    unsigned long long act = __ballot(isobj);     // wave-uniform
    int nact = __popcll(act);
    int slot_off = lane / 20;                     // 0,1,2 (lanes 60-63 -> 3: idle)
    int c = lane - slot_off * 20;                 // class index 0..19
    unsigned long long m = act;
    for (int basep = 0; basep < nact; basep += 3) {
        // wave-uniform source lanes for the 3 slots of this pass
        unsigned long long m0 = m;
        unsigned long long m1 = m0 & (m0 - 1);
        unsigned long long m2 = m1 & (m1 - 1);
        int src0 = __ffsll(m0) - 1;
        int src1 = __ffsll(m1) - 1;
        int src2 = __ffsll(m2) - 1;
        m = m2 & (m2 - 1);

        int s   = basep + slot_off;
        int src = (slot_off == 0) ? src0 : (slot_off == 1) ? src1 : src2;
        if (slot_off < 3 && s < nact) {
            // decode pair's (b, ij) from its lane index (cells are contiguous)
            int pij = ij0 + src;
            int pb  = b0;
            if (pij >= SS) { pij -= SS; pb += 1; }
            int pcell = base_cell + src;
            float t = T[(size_t)pcell * 125 + a * 25 + 5 + c];
            float l = P[((size_t)pb * 125 + a * 25 + 5 + c) * SS + pij];
            s_cls += fast_softplus(l) - l * t;
        }
    }

    // ---- wave reduce (64 lanes), then cross-wave via tiny LDS ----
    #pragma unroll
    for (int off = 32; off > 0; off >>= 1) {
        s_xywh  += __shfl_xor(s_xywh,  off, 64);
        s_cls   += __shfl_xor(s_cls,   off, 64);
        s_obj   += __shfl_xor(s_obj,   off, 64);
        s_noobj += __shfl_xor(s_noobj, off, 64);
    }
    if (lane == 0) {
        red[a][0] = s_xywh; red[a][1] = s_cls; red[a][2] = s_obj; red[a][3] = s_noobj;
    }
    __syncthreads();
    if (threadIdx.x == 0) {
        float r0 = 0, r1 = 0, r2 = 0, r3 = 0;
        #pragma unroll
        for (int w = 0; w < NA; ++w) {
            r0 += red[w][0]; r1 += red[w][1]; r2 += red[w][2]; r3 += red[w][3];
        }
        float* p = partial + (size_t)blockIdx.x * 4;
        p[0] = r0; p[1] = r1; p[2] = r2; p[3] = r3;
    }
}

__global__ __launch_bounds__(RBLOCK) void yolo_reduce(
        const float* __restrict__ partial, int n, float* __restrict__ out) {
    float v0 = 0.0f, v1 = 0.0f, v2 = 0.0f, v3 = 0.0f;
    for (int i = threadIdx.x; i < n; i += RBLOCK) {
        const float* p = partial + (size_t)i * 4;
        v0 += p[0]; v1 += p[1]; v2 += p[2]; v3 += p[3];
    }
    #pragma unroll
    for (int off = 32; off > 0; off >>= 1) {
        v0 += __shfl_xor(v0, off, 64);
        v1 += __shfl_xor(v1, off, 64);
        v2 += __shfl_xor(v2, off, 64);
        v3 += __shfl_xor(v3, off, 64);
    }
    __shared__ float red[RBLOCK / 64][4];
    int wid = threadIdx.x >> 6, lane = threadIdx.x & 63;
    if (lane == 0) {
        red[wid][0] = v0; red[wid][1] = v1; red[wid][2] = v2; red[wid][3] = v3;
    }
    __syncthreads();
    if (threadIdx.x == 0) {
        float xywh = 0, cls = 0, obj = 0, noobj = 0;
        #pragma unroll
        for (int q = 0; q < RBLOCK / 64; ++q) {
            xywh += red[q][0]; cls += red[q][1]; obj += red[q][2]; noobj += red[q][3];
        }
        out[0] = 5.0f * xywh + 5.0f * obj + 0.5f * noobj + cls;
        out[1] = xywh;
        out[2] = cls;
        out[3] = obj + noobj;
    }
}

extern "C" void kernel_launch(void* const* d_in, const int* in_sizes, int n_in,
                              void* d_out, int out_size, void* d_ws, size_t ws_size,
                              hipStream_t stream) {
    const float* P = (const float*)d_in[0];
    const float* T = (const float*)d_in[1];
    const float* anch = (const float*)d_in[2];
    float* out = (float*)d_out;
    float* partial = (float*)d_ws;   // NBLK * 4 floats = 86.5 KB

    yolo_main<<<NBLK, TPB, 0, stream>>>(P, T, anch, partial);
    yolo_reduce<<<1, RBLOCK, 0, stream>>>(partial, NBLK, out);
}